// Round 7
// baseline (842.747 us; speedup 1.0000x reference)
//
#include <hip/hip_runtime.h>
#include <cstdint>
#include <cstddef>

typedef __bf16 bf16;
typedef __bf16 bf16x8 __attribute__((ext_vector_type(8)));
typedef float f32x4 __attribute__((ext_vector_type(4)));

// ---------------------------------------------------------------------------
// NT GEMM: C[M,N] = A[M,K] @ B[N,K]^T + bias[N], f32 accum, CT out.
// f32 operands (A_F32/B_F32): load+cvt staging. bf16: vector-load staging.
// 128x128 tile, BK=32, 4 waves (2x2), each wave 64x64 = 4x4 mfma 16x16x32.
// MODE 0: C row-major [M,N]                      (CT = float -> d_out is f32!)
// MODE 1: scatter to Q/K attn layout [b][h][t][d]  (t=s*8+o/1024)
// MODE 2: scatter to V^T layout      [b][h][d][t]
// ---------------------------------------------------------------------------
template <int MODE, bool A_F32, bool B_F32, typename CT>
__global__ __launch_bounds__(256)
void gemm_nt(const void* __restrict__ Ap, const void* __restrict__ Bp,
             const float* __restrict__ bias, CT* __restrict__ C,
             int M, int N, int K) {
  __shared__ bf16 As[128 * 32];
  __shared__ bf16 Bs[128 * 32];
  const int tid = threadIdx.x;
  const int w = tid >> 6, l = tid & 63;
  const int l15 = l & 15, quad = l >> 4;
  const int tiles_n = N >> 7;
  const int tm = (blockIdx.x / tiles_n) << 7;
  const int tn = (blockIdx.x % tiles_n) << 7;
  const int wm = (w >> 1) << 6;
  const int wn = (w & 1) << 6;

  f32x4 acc[4][4] = {};

  // f32 staging geometry: each thread covers 16 elements of one row
  const int frow = tid >> 1;
  const int fch = (tid & 1) * 16;

  for (int k0 = 0; k0 < K; k0 += 32) {
    __syncthreads();
    if (A_F32) {
      const float* src = (const float*)Ap + (size_t)(tm + frow) * K + k0 + fch;
      f32x4 x0 = *(const f32x4*)(src);
      f32x4 x1 = *(const f32x4*)(src + 4);
      f32x4 x2 = *(const f32x4*)(src + 8);
      f32x4 x3 = *(const f32x4*)(src + 12);
      bf16x8 y0, y1;
#pragma unroll
      for (int j = 0; j < 4; ++j) {
        y0[j] = (bf16)x0[j]; y0[j + 4] = (bf16)x1[j];
        y1[j] = (bf16)x2[j]; y1[j + 4] = (bf16)x3[j];
      }
      *(bf16x8*)(As + frow * 32 + fch) = y0;
      *(bf16x8*)(As + frow * 32 + fch + 8) = y1;
    } else {
      const bf16* Ab = (const bf16*)Ap;
#pragma unroll
      for (int pc = 0; pc < 2; ++pc) {
        const int c = tid + pc * 256;          // 512 chunks of 16B
        const int r = c >> 2, col = (c & 3) * 8;
        *(bf16x8*)(As + r * 32 + col) =
            *(const bf16x8*)(Ab + (size_t)(tm + r) * K + k0 + col);
      }
    }
    if (B_F32) {
      const float* src = (const float*)Bp + (size_t)(tn + frow) * K + k0 + fch;
      f32x4 x0 = *(const f32x4*)(src);
      f32x4 x1 = *(const f32x4*)(src + 4);
      f32x4 x2 = *(const f32x4*)(src + 8);
      f32x4 x3 = *(const f32x4*)(src + 12);
      bf16x8 y0, y1;
#pragma unroll
      for (int j = 0; j < 4; ++j) {
        y0[j] = (bf16)x0[j]; y0[j + 4] = (bf16)x1[j];
        y1[j] = (bf16)x2[j]; y1[j + 4] = (bf16)x3[j];
      }
      *(bf16x8*)(Bs + frow * 32 + fch) = y0;
      *(bf16x8*)(Bs + frow * 32 + fch + 8) = y1;
    } else {
      const bf16* Bb = (const bf16*)Bp;
#pragma unroll
      for (int pc = 0; pc < 2; ++pc) {
        const int c = tid + pc * 256;
        const int r = c >> 2, col = (c & 3) * 8;
        *(bf16x8*)(Bs + r * 32 + col) =
            *(const bf16x8*)(Bb + (size_t)(tn + r) * K + k0 + col);
      }
    }
    __syncthreads();

    bf16x8 af[4], bfr[4];
#pragma unroll
    for (int i = 0; i < 4; ++i)
      af[i] = *(const bf16x8*)(As + (wm + i * 16 + l15) * 32 + quad * 8);
#pragma unroll
    for (int j = 0; j < 4; ++j)
      bfr[j] = *(const bf16x8*)(Bs + (wn + j * 16 + l15) * 32 + quad * 8);
#pragma unroll
    for (int i = 0; i < 4; ++i)
#pragma unroll
      for (int j = 0; j < 4; ++j)
        acc[i][j] = __builtin_amdgcn_mfma_f32_16x16x32_bf16(af[i], bfr[j], acc[i][j], 0, 0, 0);
  }

#pragma unroll
  for (int i = 0; i < 4; ++i) {
#pragma unroll
    for (int j = 0; j < 4; ++j) {
      const int n = tn + wn + j * 16 + l15;
      const float bv = bias[n];
#pragma unroll
      for (int r = 0; r < 4; ++r) {
        const int m = tm + wm + i * 16 + quad * 4 + r;
        const float v = acc[i][j][r] + bv;
        size_t idx;
        if (MODE == 0) {
          idx = (size_t)m * N + n;
        } else {
          const int b = m >> 8, s = m & 255;
          const int t = (s << 3) | (n >> 10);
          const int h = (n >> 7) & 7;
          const int d = n & 127;
          if (MODE == 1)
            idx = ((size_t)(b * 8 + h) * 2048 + t) * 128 + d;
          else
            idx = ((size_t)(b * 8 + h) * 128 + d) * 2048 + t;
        }
        C[idx] = (CT)v;
      }
    }
  }
}

// ---------------------------------------------------------------------------
// Flash attention. Q,K: [bh][2048][128], V^T: [bh][128][2048], all bf16 (ours).
// Block = 4 waves, each wave owns a 16-row q-tile; waves share K/V k-tiles (32
// keys) staged in padded LDS via plain loads. Online softmax in C-layout regs.
// Output scattered to x2 layout [b][s][f], f = (t&7)*1024 + h*128 + d.
// ---------------------------------------------------------------------------
#define KS_LD 136  // 128 + 8 pad, 272B row (16B-aligned stride)
#define VS_LD 40   // 32 + 8 pad, 80B row (16B-aligned stride)

__global__ __launch_bounds__(256)
void attn_kernel(const bf16* __restrict__ Q, const bf16* __restrict__ Kc,
                 const bf16* __restrict__ Vt, bf16* __restrict__ O2) {
  __shared__ bf16 Ks[32 * KS_LD];  // [key][d]
  __shared__ bf16 Vs[128 * VS_LD]; // [d][key]
  __shared__ bf16 Ps[4][16 * 32];  // per-wave P tile
  const int tid = threadIdx.x;
  const int w = tid >> 6, l = tid & 63;
  const int l15 = l & 15, quad = l >> 4;
  const int bh = blockIdx.x >> 5;
  const int qc = blockIdx.x & 31;
  const int b = bh >> 3, h = bh & 7;
  const int q0 = qc * 64 + w * 16;
  const size_t qkbase = (size_t)bh * 2048 * 128;
  const size_t vbase = (size_t)bh * 128 * 2048;

  // preload Q A-fragments for the whole q-tile (d = 0..127 in 4 chunks of 32)
  bf16x8 qf[4];
#pragma unroll
  for (int ds = 0; ds < 4; ++ds)
    qf[ds] = *(const bf16x8*)(Q + qkbase + (size_t)(q0 + l15) * 128 + ds * 32 + quad * 8);

  f32x4 oacc[8] = {};
  float mrow[4], lrow[4];
#pragma unroll
  for (int r = 0; r < 4; ++r) { mrow[r] = -1e30f; lrow[r] = 0.f; }

  const float iscale = 1.0f / 32.0f;

  for (int k0 = 0; k0 < 2048; k0 += 32) {
    __syncthreads();
    // K tile [32][128]: 512 chunks of 16B; thread t handles chunks t, t+256
#pragma unroll
    for (int pc = 0; pc < 2; ++pc) {
      const int c = tid + pc * 256;
      const int r = c >> 4, col = (c & 15) * 8;
      *(bf16x8*)(Ks + r * KS_LD + col) =
          *(const bf16x8*)(Kc + qkbase + (size_t)(k0 + r) * 128 + col);
    }
    // V tile [128][32]: 512 chunks of 16B
#pragma unroll
    for (int pc = 0; pc < 2; ++pc) {
      const int c = tid + pc * 256;
      const int r = c >> 2, col = (c & 3) * 8;
      *(bf16x8*)(Vs + r * VS_LD + col) =
          *(const bf16x8*)(Vt + vbase + (size_t)r * 2048 + k0 + col);
    }
    __syncthreads();

    // S = Q @ K^T : two 16x16 key tiles
    f32x4 s0 = {}, s1 = {};
#pragma unroll
    for (int ds = 0; ds < 4; ++ds) {
      bf16x8 kf0 = *(const bf16x8*)(Ks + (0 * 16 + l15) * KS_LD + ds * 32 + quad * 8);
      bf16x8 kf1 = *(const bf16x8*)(Ks + (1 * 16 + l15) * KS_LD + ds * 32 + quad * 8);
      s0 = __builtin_amdgcn_mfma_f32_16x16x32_bf16(qf[ds], kf0, s0, 0, 0, 0);
      s1 = __builtin_amdgcn_mfma_f32_16x16x32_bf16(qf[ds], kf1, s1, 0, 0, 0);
    }

    // online softmax (row quad*4+r, 16 key cols live across l15 lanes)
    float p0[4], p1[4], al[4];
#pragma unroll
    for (int r = 0; r < 4; ++r) {
      const float a = s0[r] * iscale, c = s1[r] * iscale;
      float mx = fmaxf(a, c);
      mx = fmaxf(mx, __shfl_xor(mx, 1));
      mx = fmaxf(mx, __shfl_xor(mx, 2));
      mx = fmaxf(mx, __shfl_xor(mx, 4));
      mx = fmaxf(mx, __shfl_xor(mx, 8));
      const float mnew = fmaxf(mrow[r], mx);
      const float alpha = __expf(mrow[r] - mnew);
      mrow[r] = mnew;
      const float e0 = __expf(a - mnew), e1 = __expf(c - mnew);
      float rs = e0 + e1;
      rs += __shfl_xor(rs, 1);
      rs += __shfl_xor(rs, 2);
      rs += __shfl_xor(rs, 4);
      rs += __shfl_xor(rs, 8);
      lrow[r] = lrow[r] * alpha + rs;
      p0[r] = e0; p1[r] = e1; al[r] = alpha;
    }
#pragma unroll
    for (int dt = 0; dt < 8; ++dt)
#pragma unroll
      for (int r = 0; r < 4; ++r) oacc[dt][r] *= al[r];

    // P: C-layout -> LDS -> A-layout (barrier-protected)
    bf16* pl = &Ps[w][0];
#pragma unroll
    for (int r = 0; r < 4; ++r) {
      pl[(quad * 4 + r) * 32 + l15] = (bf16)p0[r];
      pl[(quad * 4 + r) * 32 + l15 + 16] = (bf16)p1[r];
    }
    __syncthreads();
    bf16x8 pf = *(const bf16x8*)(pl + l15 * 32 + quad * 8);

    // O += P @ V : 8 d-tiles of 16
#pragma unroll
    for (int dt = 0; dt < 8; ++dt) {
      bf16x8 vf = *(const bf16x8*)(Vs + (dt * 16 + l15) * VS_LD + quad * 8);
      oacc[dt] = __builtin_amdgcn_mfma_f32_16x16x32_bf16(pf, vf, oacc[dt], 0, 0, 0);
    }
  }

  // epilogue: O2[b][s][f], f = (t&7)*1024 + h*128 + d
#pragma unroll
  for (int dt = 0; dt < 8; ++dt) {
#pragma unroll
    for (int r = 0; r < 4; ++r) {
      const int t = q0 + quad * 4 + r;
      const int d = dt * 16 + l15;
      const int s = t >> 3;
      const int f = (t & 7) * 1024 + h * 128 + d;
      O2[(size_t)(b * 256 + s) * 8192 + f] = (bf16)(oacc[dt][r] / lrow[r]);
    }
  }
}

extern "C" void kernel_launch(void* const* d_in, const int* in_sizes, int n_in,
                              void* d_out, int out_size, void* d_ws, size_t ws_size,
                              hipStream_t stream) {
  const float* query = (const float*)d_in[0];
  const float* key_ = (const float*)d_in[1];
  const float* value = (const float*)d_in[2];
  const float* Wq = (const float*)d_in[3];
  const float* bq = (const float*)d_in[4];
  const float* Wk = (const float*)d_in[5];
  const float* bk = (const float*)d_in[6];
  const float* Wv = (const float*)d_in[7];
  const float* bv = (const float*)d_in[8];
  const float* Wfc = (const float*)d_in[9];
  const float* bfc = (const float*)d_in[10];
  float* out = (float*)d_out;  // reference output dtype is FLOAT32

  const size_t T8M = (size_t)8 * 1024 * 1024;  // 8M bf16 = 16MB per region
  bf16* Qws = (bf16*)d_ws;
  bf16* Kws = Qws + T8M;
  bf16* Vtw = Kws + T8M;
  bf16* O2 = Vtw + T8M;  // 64MB total (ws_size >= 64MB verified in round 5)

  dim3 blk(256);
  // projections: M=1024, N=8192, K=1024 -> 512 blocks (f32 A, f32 B)
  gemm_nt<1, true, true, bf16><<<512, blk, 0, stream>>>(query, Wq, bq, Qws, 1024, 8192, 1024);
  gemm_nt<1, true, true, bf16><<<512, blk, 0, stream>>>(key_, Wk, bk, Kws, 1024, 8192, 1024);
  gemm_nt<2, true, true, bf16><<<512, blk, 0, stream>>>(value, Wv, bv, Vtw, 1024, 8192, 1024);
  // attention: 32 (b,h) x 32 q-chunks of 64 rows
  attn_kernel<<<1024, blk, 0, stream>>>(Qws, Kws, Vtw, O2);
  // output projection: M=1024, N=1024, K=8192 -> 64 blocks (bf16 A, f32 B), f32 out
  gemm_nt<0, false, true, float><<<64, blk, 0, stream>>>(O2, Wfc, bfc, out, 1024, 1024, 8192);
}

// Round 8
// 599.252 us; speedup vs baseline: 1.4063x; 1.4063x over previous
//
#include <hip/hip_runtime.h>
#include <cstdint>
#include <cstddef>

typedef __bf16 bf16;
typedef __bf16 bf16x8 __attribute__((ext_vector_type(8)));
typedef float f32x4 __attribute__((ext_vector_type(4)));

#define SLD 40  // LDS row stride (elements): 80B -> 2-way (free) bank pattern

// ---------------------------------------------------------------------------
// NT GEMM: C[M,N] = A[M,K] @ B[N,K]^T + bias[N], f32 accum.
// f32 operands (A_F32/B_F32): load+cvt staging. bf16: vector-load staging.
// 128x128 tile, BK=32, 4 waves (2x2), each wave 64x64 = 4x4 mfma 16x16x32.
// MODE 0: C row-major [M,N], bias added          (CT=float for d_out)
// MODE 1: scatter to Q/K attn layout [b][h][t][d]  (t=s*8+o/1024)
// MODE 2: scatter to V^T layout      [b][h][d][t]
// MODE 3: split-K partial: blockIdx.y owns K-slice of 1024, writes f32
//         partial (no bias) at C + blockIdx.y*M*N.
// ---------------------------------------------------------------------------
template <int MODE, bool A_F32, bool B_F32, typename CT>
__global__ __launch_bounds__(256)
void gemm_nt(const void* __restrict__ Ap, const void* __restrict__ Bp,
             const float* __restrict__ bias, CT* __restrict__ C,
             int M, int N, int K) {
  __shared__ bf16 As[128 * SLD];
  __shared__ bf16 Bs[128 * SLD];
  const int tid = threadIdx.x;
  const int w = tid >> 6, l = tid & 63;
  const int l15 = l & 15, quad = l >> 4;
  const int tiles_n = N >> 7;
  const int tm = (blockIdx.x / tiles_n) << 7;
  const int tn = (blockIdx.x % tiles_n) << 7;
  const int wm = (w >> 1) << 6;
  const int wn = (w & 1) << 6;

  f32x4 acc[4][4] = {};

  // f32 staging geometry: each thread covers 16 elements of one row
  const int frow = tid >> 1;
  const int fch = (tid & 1) * 16;

  const int kbeg = (MODE == 3) ? blockIdx.y * 1024 : 0;
  const int kend = (MODE == 3) ? kbeg + 1024 : K;

  for (int k0 = kbeg; k0 < kend; k0 += 32) {
    __syncthreads();
    if (A_F32) {
      const float* src = (const float*)Ap + (size_t)(tm + frow) * K + k0 + fch;
      f32x4 x0 = *(const f32x4*)(src);
      f32x4 x1 = *(const f32x4*)(src + 4);
      f32x4 x2 = *(const f32x4*)(src + 8);
      f32x4 x3 = *(const f32x4*)(src + 12);
      bf16x8 y0, y1;
#pragma unroll
      for (int j = 0; j < 4; ++j) {
        y0[j] = (bf16)x0[j]; y0[j + 4] = (bf16)x1[j];
        y1[j] = (bf16)x2[j]; y1[j + 4] = (bf16)x3[j];
      }
      *(bf16x8*)(As + frow * SLD + fch) = y0;
      *(bf16x8*)(As + frow * SLD + fch + 8) = y1;
    } else {
      const bf16* Ab = (const bf16*)Ap;
#pragma unroll
      for (int pc = 0; pc < 2; ++pc) {
        const int c = tid + pc * 256;          // 512 chunks of 16B
        const int r = c >> 2, col = (c & 3) * 8;
        *(bf16x8*)(As + r * SLD + col) =
            *(const bf16x8*)(Ab + (size_t)(tm + r) * K + k0 + col);
      }
    }
    if (B_F32) {
      const float* src = (const float*)Bp + (size_t)(tn + frow) * K + k0 + fch;
      f32x4 x0 = *(const f32x4*)(src);
      f32x4 x1 = *(const f32x4*)(src + 4);
      f32x4 x2 = *(const f32x4*)(src + 8);
      f32x4 x3 = *(const f32x4*)(src + 12);
      bf16x8 y0, y1;
#pragma unroll
      for (int j = 0; j < 4; ++j) {
        y0[j] = (bf16)x0[j]; y0[j + 4] = (bf16)x1[j];
        y1[j] = (bf16)x2[j]; y1[j + 4] = (bf16)x3[j];
      }
      *(bf16x8*)(Bs + frow * SLD + fch) = y0;
      *(bf16x8*)(Bs + frow * SLD + fch + 8) = y1;
    } else {
      const bf16* Bb = (const bf16*)Bp;
#pragma unroll
      for (int pc = 0; pc < 2; ++pc) {
        const int c = tid + pc * 256;
        const int r = c >> 2, col = (c & 3) * 8;
        *(bf16x8*)(Bs + r * SLD + col) =
            *(const bf16x8*)(Bb + (size_t)(tn + r) * K + k0 + col);
      }
    }
    __syncthreads();

    bf16x8 af[4], bfr[4];
#pragma unroll
    for (int i = 0; i < 4; ++i)
      af[i] = *(const bf16x8*)(As + (wm + i * 16 + l15) * SLD + quad * 8);
#pragma unroll
    for (int j = 0; j < 4; ++j)
      bfr[j] = *(const bf16x8*)(Bs + (wn + j * 16 + l15) * SLD + quad * 8);
#pragma unroll
    for (int i = 0; i < 4; ++i)
#pragma unroll
      for (int j = 0; j < 4; ++j)
        acc[i][j] = __builtin_amdgcn_mfma_f32_16x16x32_bf16(af[i], bfr[j], acc[i][j], 0, 0, 0);
  }

  const size_t koff = (MODE == 3) ? (size_t)blockIdx.y * M * N : 0;
#pragma unroll
  for (int i = 0; i < 4; ++i) {
#pragma unroll
    for (int j = 0; j < 4; ++j) {
      const int n = tn + wn + j * 16 + l15;
      const float bv = (MODE == 3) ? 0.f : bias[n];
#pragma unroll
      for (int r = 0; r < 4; ++r) {
        const int m = tm + wm + i * 16 + quad * 4 + r;
        const float v = acc[i][j][r] + bv;
        size_t idx;
        if (MODE == 0 || MODE == 3) {
          idx = koff + (size_t)m * N + n;
        } else {
          const int b = m >> 8, s = m & 255;
          const int t = (s << 3) | (n >> 10);
          const int h = (n >> 7) & 7;
          const int d = n & 127;
          if (MODE == 1)
            idx = ((size_t)(b * 8 + h) * 2048 + t) * 128 + d;
          else
            idx = ((size_t)(b * 8 + h) * 128 + d) * 2048 + t;
        }
        C[idx] = (CT)v;
      }
    }
  }
}

// Sum 8 split-K partials + bias -> f32 out. 1024x1024 elements, f32x4.
__global__ __launch_bounds__(256)
void splitk_reduce(const float* __restrict__ P, const float* __restrict__ bias,
                   float* __restrict__ out) {
  const int i = (blockIdx.x * 256 + threadIdx.x) * 4;  // element index
  const int n = i & 1023;
  f32x4 s = *(const f32x4*)(bias + n);
#pragma unroll
  for (int kc = 0; kc < 8; ++kc)
    s += *(const f32x4*)(P + (size_t)kc * 1048576 + i);
  *(f32x4*)(out + i) = s;
}

// ---------------------------------------------------------------------------
// Flash attention. Q,K: [bh][2048][128], V^T: [bh][128][2048], all bf16 (ours).
// Block = 4 waves, each wave owns a 16-row q-tile; waves share K/V k-tiles (32
// keys) staged in padded LDS via plain loads. Online softmax in C-layout regs.
// Output scattered to x2 layout [b][s][f], f = (t&7)*1024 + h*128 + d.
// ---------------------------------------------------------------------------
#define KS_LD 136  // 128 + 8 pad
#define VS_LD 40   // 32 + 8 pad

__global__ __launch_bounds__(256)
void attn_kernel(const bf16* __restrict__ Q, const bf16* __restrict__ Kc,
                 const bf16* __restrict__ Vt, bf16* __restrict__ O2) {
  __shared__ bf16 Ks[32 * KS_LD];  // [key][d]
  __shared__ bf16 Vs[128 * VS_LD]; // [d][key]
  __shared__ bf16 Ps[4][16 * 32];  // per-wave P tile
  const int tid = threadIdx.x;
  const int w = tid >> 6, l = tid & 63;
  const int l15 = l & 15, quad = l >> 4;
  const int bh = blockIdx.x >> 5;
  const int qc = blockIdx.x & 31;
  const int b = bh >> 3, h = bh & 7;
  const int q0 = qc * 64 + w * 16;
  const size_t qkbase = (size_t)bh * 2048 * 128;
  const size_t vbase = (size_t)bh * 128 * 2048;

  bf16x8 qf[4];
#pragma unroll
  for (int ds = 0; ds < 4; ++ds)
    qf[ds] = *(const bf16x8*)(Q + qkbase + (size_t)(q0 + l15) * 128 + ds * 32 + quad * 8);

  f32x4 oacc[8] = {};
  float mrow[4], lrow[4];
#pragma unroll
  for (int r = 0; r < 4; ++r) { mrow[r] = -1e30f; lrow[r] = 0.f; }

  const float iscale = 1.0f / 32.0f;

  for (int k0 = 0; k0 < 2048; k0 += 32) {
    __syncthreads();
#pragma unroll
    for (int pc = 0; pc < 2; ++pc) {
      const int c = tid + pc * 256;
      const int r = c >> 4, col = (c & 15) * 8;
      *(bf16x8*)(Ks + r * KS_LD + col) =
          *(const bf16x8*)(Kc + qkbase + (size_t)(k0 + r) * 128 + col);
    }
#pragma unroll
    for (int pc = 0; pc < 2; ++pc) {
      const int c = tid + pc * 256;
      const int r = c >> 2, col = (c & 3) * 8;
      *(bf16x8*)(Vs + r * VS_LD + col) =
          *(const bf16x8*)(Vt + vbase + (size_t)r * 2048 + k0 + col);
    }
    __syncthreads();

    f32x4 s0 = {}, s1 = {};
#pragma unroll
    for (int ds = 0; ds < 4; ++ds) {
      bf16x8 kf0 = *(const bf16x8*)(Ks + (0 * 16 + l15) * KS_LD + ds * 32 + quad * 8);
      bf16x8 kf1 = *(const bf16x8*)(Ks + (1 * 16 + l15) * KS_LD + ds * 32 + quad * 8);
      s0 = __builtin_amdgcn_mfma_f32_16x16x32_bf16(qf[ds], kf0, s0, 0, 0, 0);
      s1 = __builtin_amdgcn_mfma_f32_16x16x32_bf16(qf[ds], kf1, s1, 0, 0, 0);
    }

    float p0[4], p1[4], al[4];
#pragma unroll
    for (int r = 0; r < 4; ++r) {
      const float a = s0[r] * iscale, c = s1[r] * iscale;
      float mx = fmaxf(a, c);
      mx = fmaxf(mx, __shfl_xor(mx, 1));
      mx = fmaxf(mx, __shfl_xor(mx, 2));
      mx = fmaxf(mx, __shfl_xor(mx, 4));
      mx = fmaxf(mx, __shfl_xor(mx, 8));
      const float mnew = fmaxf(mrow[r], mx);
      const float alpha = __expf(mrow[r] - mnew);
      mrow[r] = mnew;
      const float e0 = __expf(a - mnew), e1 = __expf(c - mnew);
      float rs = e0 + e1;
      rs += __shfl_xor(rs, 1);
      rs += __shfl_xor(rs, 2);
      rs += __shfl_xor(rs, 4);
      rs += __shfl_xor(rs, 8);
      lrow[r] = lrow[r] * alpha + rs;
      p0[r] = e0; p1[r] = e1; al[r] = alpha;
    }
#pragma unroll
    for (int dt = 0; dt < 8; ++dt)
#pragma unroll
      for (int r = 0; r < 4; ++r) oacc[dt][r] *= al[r];

    bf16* pl = &Ps[w][0];
#pragma unroll
    for (int r = 0; r < 4; ++r) {
      pl[(quad * 4 + r) * 32 + l15] = (bf16)p0[r];
      pl[(quad * 4 + r) * 32 + l15 + 16] = (bf16)p1[r];
    }
    __syncthreads();
    bf16x8 pf = *(const bf16x8*)(pl + l15 * 32 + quad * 8);

#pragma unroll
    for (int dt = 0; dt < 8; ++dt) {
      bf16x8 vf = *(const bf16x8*)(Vs + (dt * 16 + l15) * VS_LD + quad * 8);
      oacc[dt] = __builtin_amdgcn_mfma_f32_16x16x32_bf16(pf, vf, oacc[dt], 0, 0, 0);
    }
  }

#pragma unroll
  for (int dt = 0; dt < 8; ++dt) {
#pragma unroll
    for (int r = 0; r < 4; ++r) {
      const int t = q0 + quad * 4 + r;
      const int d = dt * 16 + l15;
      const int s = t >> 3;
      const int f = (t & 7) * 1024 + h * 128 + d;
      O2[(size_t)(b * 256 + s) * 8192 + f] = (bf16)(oacc[dt][r] / lrow[r]);
    }
  }
}

extern "C" void kernel_launch(void* const* d_in, const int* in_sizes, int n_in,
                              void* d_out, int out_size, void* d_ws, size_t ws_size,
                              hipStream_t stream) {
  const float* query = (const float*)d_in[0];
  const float* key_ = (const float*)d_in[1];
  const float* value = (const float*)d_in[2];
  const float* Wq = (const float*)d_in[3];
  const float* bq = (const float*)d_in[4];
  const float* Wk = (const float*)d_in[5];
  const float* bk = (const float*)d_in[6];
  const float* Wv = (const float*)d_in[7];
  const float* bv = (const float*)d_in[8];
  const float* Wfc = (const float*)d_in[9];
  const float* bfc = (const float*)d_in[10];
  float* out = (float*)d_out;  // output dtype is FLOAT32 (verified round 7)

  const size_t T8M = (size_t)8 * 1024 * 1024;  // 8M bf16 = 16MB per region
  bf16* Qws = (bf16*)d_ws;
  bf16* Kws = Qws + T8M;
  bf16* Vtw = Kws + T8M;
  bf16* O2 = Vtw + T8M;  // 64MB total (ws_size >= 64MB verified round 5)
  // split-K partials (8 x 1024x1024 f32 = 32MB) reuse Q/K regions, which are
  // dead after attn_kernel.
  float* Pk = (float*)d_ws;

  dim3 blk(256);
  // projections: M=1024, N=8192, K=1024 -> 512 blocks (f32 A, f32 B)
  gemm_nt<1, true, true, bf16><<<512, blk, 0, stream>>>(query, Wq, bq, Qws, 1024, 8192, 1024);
  gemm_nt<1, true, true, bf16><<<512, blk, 0, stream>>>(key_, Wk, bk, Kws, 1024, 8192, 1024);
  gemm_nt<2, true, true, bf16><<<512, blk, 0, stream>>>(value, Wv, bv, Vtw, 1024, 8192, 1024);
  // attention: 32 (b,h) x 32 q-chunks of 64 rows
  attn_kernel<<<1024, blk, 0, stream>>>(Qws, Kws, Vtw, O2);
  // output projection, split-K x8: grid (64 tiles, 8 K-slices)
  gemm_nt<3, false, true, float><<<dim3(64, 8), blk, 0, stream>>>(O2, Wfc, nullptr, Pk, 1024, 1024, 8192);
  splitk_reduce<<<1024, blk, 0, stream>>>(Pk, bfc, out);
}